// Round 6
// baseline (57.149 us; speedup 1.0000x reference)
//
#include <hip/hip_runtime.h>
#include <hip/hip_bf16.h>

#define B_   32
#define N_   2048
#define VD_  512
#define AD_  128
#define SD_  128
#define TM   64
#define THREADS 256

typedef __attribute__((ext_vector_type(8))) short short8;
typedef __attribute__((ext_vector_type(4))) float f32x4;

// ws layout (ushort element offsets) for fragment-packed bf16 weights.
// Packing: for W[C][K], frag (n,kc,l,e): dst[((n*(K/32)+kc)*64+l)*8+e] = W[n*16+(l&15)][kc*32+(l>>4)*8+e]
#define WOFF_VFC 0        // C=128,K=512: 65536
#define WOFF_AFC 65536    // C=128,K=128: 16384
#define WOFF_AM  81920    // C=128,K=128: 16384
#define WOFF_V   98304    // C=64, K=128: 8192
#define WOFF_U   106496   // C=64, K=128: 8192
#define WTOT     114688   // ushorts = 229376 bytes; zpart follows

__device__ __forceinline__ float sigmoidf_(float x) { return 1.0f / (1.0f + __expf(-x)); }

__device__ __forceinline__ ushort f2bf(float x) {   // RNE
    union { float f; unsigned int i; } v; v.f = x;
    unsigned int r = v.i + 0x7FFFu + ((v.i >> 16) & 1u);
    return (ushort)(r >> 16);
}
__device__ __forceinline__ float bf2f(ushort u) {
    union { unsigned int i; float f; } v; v.i = ((unsigned int)u) << 16; return v.f;
}
// Xbuf swizzle: ushort [R][128], XOR on 16B chunks
__device__ __forceinline__ int swz(int row, int k, int ldk) {
    return row * ldk + (k ^ ((row & 7) << 3));
}
// Abuf swizzle: f32 [64][32], (row, 16B-chunk c) -> f32 index
__device__ __forceinline__ int fswz(int row, int c) {
    return row * 32 + ((c ^ (row & 7)) << 2);
}
// 8x f32 -> 8x bf16 via packed convert (RNE), 4 instructions
__device__ __forceinline__ short8 pack8(float4 x, float4 y) {
    union { unsigned int u[4]; short8 s; } o;
    asm("v_cvt_pk_bf16_f32 %0, %1, %2" : "=v"(o.u[0]) : "v"(x.x), "v"(x.y));
    asm("v_cvt_pk_bf16_f32 %0, %1, %2" : "=v"(o.u[1]) : "v"(x.z), "v"(x.w));
    asm("v_cvt_pk_bf16_f32 %0, %1, %2" : "=v"(o.u[2]) : "v"(y.x), "v"(y.y));
    asm("v_cvt_pk_bf16_f32 %0, %1, %2" : "=v"(o.u[3]) : "v"(y.z), "v"(y.w));
    return o.s;
}
template<int N> __device__ __forceinline__ void vmwait() {
    if constexpr (N == 0) asm volatile("s_waitcnt vmcnt(0)" ::: "memory");
    else if constexpr (N == 6) asm volatile("s_waitcnt vmcnt(6)" ::: "memory");
}

// Stage one [64][32]-f32 K-chunk (8KB) via global_load_lds; linear LDS dest,
// inverse-swizzled global source (both-sides rule, G21).
__device__ __forceinline__ void stage64(const float* __restrict__ src, int ldK, int kcol,
                                        float* lds_base, int wid, int lane)
{
    #pragma unroll
    for (int i = 0; i < 2; ++i) {
        int D   = i * 256 + wid * 64 + lane;          // 16B-chunk id, 0..511
        int row = D >> 3, jj = D & 7;
        int j   = jj ^ (row & 7);
        const float* gp = src + (size_t)row * ldK + kcol + j * 4;
        float* lp = lds_base + (i * 256 + wid * 64) * 4;   // wave-uniform base
        __builtin_amdgcn_global_load_lds((const __attribute__((address_space(1))) void*)gp,
                                         (__attribute__((address_space(3))) void*)lp, 16, 0, 0);
    }
}

// ---- weight pre-conversion + fragment packing ----
__global__ __launch_bounds__(256)
void cvt_weights(const float* __restrict__ vfc, const float* __restrict__ afc,
                 const float* __restrict__ am,  const float* __restrict__ Vw,
                 const float* __restrict__ Uw,  ushort* __restrict__ dst)
{
    int f = blockIdx.x * 256 + threadIdx.x;
    if (f >= WTOT / 8) return;
    int e0 = f * 8;
    const float* src; int base, K;
    if      (e0 < WOFF_AFC) { src = vfc; base = WOFF_VFC; K = 512; }
    else if (e0 < WOFF_AM)  { src = afc; base = WOFF_AFC; K = 128; }
    else if (e0 < WOFF_V)   { src = am;  base = WOFF_AM;  K = 128; }
    else if (e0 < WOFF_U)   { src = Vw;  base = WOFF_V;   K = 128; }
    else                    { src = Uw;  base = WOFF_U;   K = 128; }
    int lf = f - base / 8;
    int l = lf & 63, rem = lf >> 6;
    int NK = K / 32;
    int kc = rem % NK, n = rem / NK;
    int tc = l & 15, g4 = l >> 4;
    const float* sp = src + (size_t)(n * 16 + tc) * K + kc * 32 + g4 * 8;
    float4 x = ((const float4*)sp)[0], y = ((const float4*)sp)[1];
    short8 o = pack8(x, y);
    *(short8*)(dst + e0) = o;
}

// issue the first two A-chunks of a staged GEMM
template<int K>
__device__ __forceinline__ void stage_head(const float* __restrict__ Asrc,
                                           float (*Ab)[TM * 32], int wid, int lane)
{
    stage64(Asrc, K, 0,  Ab[0], wid, lane);
    stage64(Asrc, K, 32, Ab[1], wid, lane);
}

// Counted-vmcnt pipelined staged GEMM. Prereq: stage_head<K> already issued
// (chunks 0,1 into Ab[0],Ab[1]); any intervening VMEM fully consumed (drained).
// Per iter: wait vmcnt(6) [= s(kc+1)+p(kc+1) younger], barrier, issue s(kc+2)+p(kc+2).
template<int K>
__device__ __forceinline__ void pipe_loop(const float* __restrict__ Asrc,
                                          const ushort* __restrict__ Bp,
                                          float (*Ab)[TM * 32],
                                          int wid, int lane, int wr, int wc, int t16, int g4,
                                          f32x4 (&acc)[2][4])
{
    constexpr int NC = K / 32;
    const ushort* bp = Bp + (size_t)(4 * wc) * NC * 512 + lane * 8;
    short8 pbuf[2][4];
    #pragma unroll
    for (int n = 0; n < 4; ++n) pbuf[0][n] = *(const short8*)(bp + (size_t)n * NC * 512);
    #pragma unroll
    for (int n = 0; n < 4; ++n) pbuf[1][n] = *(const short8*)(bp + 512 + (size_t)n * NC * 512);

    #pragma unroll
    for (int kc = 0; kc < NC; ++kc) {
        if (kc + 1 < NC) vmwait<6>(); else vmwait<0>();
        __builtin_amdgcn_s_barrier();
        __builtin_amdgcn_sched_barrier(0);
        short8 b0 = pbuf[kc & 1][0], b1 = pbuf[kc & 1][1];
        short8 b2 = pbuf[kc & 1][2], b3 = pbuf[kc & 1][3];
        if (kc + 2 < NC) {
            stage64(Asrc, K, (kc + 2) * 32, Ab[(kc + 2) % 3], wid, lane);
            #pragma unroll
            for (int n = 0; n < 4; ++n)
                pbuf[kc & 1][n] = *(const short8*)(bp + (size_t)(kc + 2) * 512 + (size_t)n * NC * 512);
        }
        const float* cur = Ab[kc % 3];
        int row0 = 32 * wr + t16;
        float4 x0 = *(const float4*)&cur[fswz(row0,      2 * g4)];
        float4 y0 = *(const float4*)&cur[fswz(row0,      2 * g4 + 1)];
        float4 x1 = *(const float4*)&cur[fswz(row0 + 16, 2 * g4)];
        float4 y1 = *(const float4*)&cur[fswz(row0 + 16, 2 * g4 + 1)];
        short8 a0 = pack8(x0, y0), a1 = pack8(x1, y1);
        acc[0][0] = __builtin_amdgcn_mfma_f32_16x16x32_bf16(a0, b0, acc[0][0], 0, 0, 0);
        acc[1][0] = __builtin_amdgcn_mfma_f32_16x16x32_bf16(a1, b0, acc[1][0], 0, 0, 0);
        acc[0][1] = __builtin_amdgcn_mfma_f32_16x16x32_bf16(a0, b1, acc[0][1], 0, 0, 0);
        acc[1][1] = __builtin_amdgcn_mfma_f32_16x16x32_bf16(a1, b1, acc[1][1], 0, 0, 0);
        acc[0][2] = __builtin_amdgcn_mfma_f32_16x16x32_bf16(a0, b2, acc[0][2], 0, 0, 0);
        acc[1][2] = __builtin_amdgcn_mfma_f32_16x16x32_bf16(a1, b2, acc[1][2], 0, 0, 0);
        acc[0][3] = __builtin_amdgcn_mfma_f32_16x16x32_bf16(a0, b3, acc[0][3], 0, 0, 0);
        acc[1][3] = __builtin_amdgcn_mfma_f32_16x16x32_bf16(a1, b3, acc[1][3], 0, 0, 0);
    }
}

// GEMM with A from swizzled LDS bf16 (Xbuf), B fragment-packed global.
template<int K>
__device__ __forceinline__ void gemm_lp(const ushort* __restrict__ Ab,
                                        const ushort* __restrict__ Bp,
                                        int wr, int wc, int t16, int g4, int lane,
                                        f32x4 (&acc)[2][4])
{
    constexpr int NK = K / 32;
    const ushort* bp = Bp + (size_t)(4 * wc) * NK * 512 + lane * 8;
    short8 pb[4];
    #pragma unroll
    for (int n = 0; n < 4; ++n) pb[n] = *(const short8*)(bp + (size_t)n * NK * 512);

    #pragma unroll
    for (int kc = 0; kc < NK; ++kc) {
        int k = kc * 32 + g4 * 8;
        short8 a0 = *(const short8*)&Ab[swz(32 * wr + t16,      k, 128)];
        short8 a1 = *(const short8*)&Ab[swz(32 * wr + 16 + t16, k, 128)];
        short8 b0 = pb[0], b1 = pb[1], b2 = pb[2], b3 = pb[3];
        if (kc + 1 < NK) {
            #pragma unroll
            for (int n = 0; n < 4; ++n)
                pb[n] = *(const short8*)(bp + (size_t)(kc + 1) * 512 + (size_t)n * NK * 512);
        }
        acc[0][0] = __builtin_amdgcn_mfma_f32_16x16x32_bf16(a0, b0, acc[0][0], 0, 0, 0);
        acc[1][0] = __builtin_amdgcn_mfma_f32_16x16x32_bf16(a1, b0, acc[1][0], 0, 0, 0);
        acc[0][1] = __builtin_amdgcn_mfma_f32_16x16x32_bf16(a0, b1, acc[0][1], 0, 0, 0);
        acc[1][1] = __builtin_amdgcn_mfma_f32_16x16x32_bf16(a1, b1, acc[1][1], 0, 0, 0);
        acc[0][2] = __builtin_amdgcn_mfma_f32_16x16x32_bf16(a0, b2, acc[0][2], 0, 0, 0);
        acc[1][2] = __builtin_amdgcn_mfma_f32_16x16x32_bf16(a1, b2, acc[1][2], 0, 0, 0);
        acc[0][3] = __builtin_amdgcn_mfma_f32_16x16x32_bf16(a0, b3, acc[0][3], 0, 0, 0);
        acc[1][3] = __builtin_amdgcn_mfma_f32_16x16x32_bf16(a1, b3, acc[1][3], 0, 0, 0);
    }
}

// Grid: 32 b x 32 tiles = 1024 blocks, 256 threads (4 waves).
// LDS = 16KB Xbuf + 3x8KB Abuf = 40KB exactly -> 4 blocks/CU, 16 waves/CU.
__global__ __launch_bounds__(THREADS, 4)
void fused_mil(const float* __restrict__ vfeat, const float* __restrict__ afeat,
               const ushort* __restrict__ wsW,
               const float* __restrict__ afc_b, const float* __restrict__ am_b,
               const float* __restrict__ vfc_b,
               const float* __restrict__ V_b,   const float* __restrict__ U_b,
               const float* __restrict__ W_w,   const float* __restrict__ W_b,
               float* __restrict__ s_out, float* __restrict__ zpart)
{
    __shared__ __align__(16) ushort Xbuf[TM * 128];    // ax -> gate -> ffeat (aliased), 16KB
    __shared__ __align__(16) float  Abuf[3][TM * 32];  // staged A K-chunks, 3x8KB

    // score/pool scratch aliased into Abuf (free after phase C)
    float* sPb = (float*)Abuf;        // [2][64]
    float* sSb = sPb + 128;           // [64]
    float* zqb = sSb + 64;            // [2][128]

    const int tid  = threadIdx.x;
    const int bx   = blockIdx.x;
    const int b    = bx >> 5;
    const int tok0 = (bx & 31) * TM;
    const int wid  = tid >> 6;
    const int lane = tid & 63;
    const int t16  = lane & 15;
    const int g4   = lane >> 4;
    const int wr   = wid >> 1;
    const int wc   = wid & 1;

    const float* afeat_t = afeat + ((size_t)b * N_ + tok0) * AD_;
    const float* vfeat_t = vfeat + ((size_t)b * N_ + tok0) * VD_;

    f32x4 acc[2][4];

    // ---- Phase A: ax = relu(afeat @ afc_w^T + afc_b) -> Xbuf ----
    stage_head<AD_>(afeat_t, Abuf, wid, lane);
    #pragma unroll
    for (int m = 0; m < 2; ++m)
        #pragma unroll
        for (int n = 0; n < 4; ++n) acc[m][n] = (f32x4)0.0f;
    pipe_loop<AD_>(afeat_t, wsW + WOFF_AFC, Abuf, wid, lane, wr, wc, t16, g4, acc);
    #pragma unroll
    for (int n = 0; n < 4; ++n) {
        int c = 64 * wc + 16 * n + t16;
        float bias = afc_b[c];
        #pragma unroll
        for (int m = 0; m < 2; ++m)
            #pragma unroll
            for (int r = 0; r < 4; ++r) {
                int row = 32 * wr + 16 * m + 4 * g4 + r;
                Xbuf[swz(row, c, 128)] = f2bf(fmaxf(acc[m][n][r] + bias, 0.0f));
            }
    }
    __syncthreads();                                   // ax visible; Abuf reads done

    // early-issue phase C chunks 0,1 (16KB flies under phase B)
    stage_head<VD_>(vfeat_t, Abuf, wid, lane);

    // ---- Phase B: gate = sigmoid(ax @ am_w^T + am_b), stashed bf16 into Xbuf ----
    #pragma unroll
    for (int m = 0; m < 2; ++m)
        #pragma unroll
        for (int n = 0; n < 4; ++n) acc[m][n] = (f32x4)0.0f;
    gemm_lp<SD_>(Xbuf, wsW + WOFF_AM, wr, wc, t16, g4, lane, acc);
    __syncthreads();                                   // everyone done reading ax
    #pragma unroll
    for (int n = 0; n < 4; ++n) {
        int c = 64 * wc + 16 * n + t16;
        float bias = am_b[c];
        #pragma unroll
        for (int m = 0; m < 2; ++m)
            #pragma unroll
            for (int r = 0; r < 4; ++r) {
                int row = 32 * wr + 16 * m + 4 * g4 + r;
                Xbuf[swz(row, c, 128)] = f2bf(sigmoidf_(acc[m][n][r] + bias));
            }
    }
    // no barrier: phase C touches no Xbuf; gate cells thread-private

    // ---- Phase C: vo1 = vfeat @ vfc_w^T (K=512, counted-vmcnt pipeline) ----
    #pragma unroll
    for (int m = 0; m < 2; ++m)
        #pragma unroll
        for (int n = 0; n < 4; ++n) acc[m][n] = (f32x4)0.0f;
    pipe_loop<VD_>(vfeat_t, wsW + WOFF_VFC, Abuf, wid, lane, wr, wc, t16, g4, acc);

    // epilogue: ffeat = relu(vo1+b) * (1 + gate) -> Xbuf (thread-private cells)
    #pragma unroll
    for (int n = 0; n < 4; ++n) {
        int c = 64 * wc + 16 * n + t16;
        float vb = vfc_b[c];
        #pragma unroll
        for (int m = 0; m < 2; ++m)
            #pragma unroll
            for (int r = 0; r < 4; ++r) {
                int row = 32 * wr + 16 * m + 4 * g4 + r;
                float g   = bf2f(Xbuf[swz(row, c, 128)]);
                float vo1 = fmaxf(acc[m][n][r] + vb, 0.0f);
                Xbuf[swz(row, c, 128)] = f2bf(vo1 * (1.0f + g));
            }
    }
    __syncthreads();

    // ---- Phase E: v/u heads. n=0,1: V tiles 2wc+n; n=2,3: U tiles 2wc+(n-2). ----
    #pragma unroll
    for (int m = 0; m < 2; ++m)
        #pragma unroll
        for (int n = 0; n < 4; ++n) acc[m][n] = (f32x4)0.0f;
    {
        const ushort* Vp = wsW + WOFF_V;   // C=64,K=128 -> NK=4, per-tile 4*512
        const ushort* Up = wsW + WOFF_U;
        short8 pb[4];
        pb[0] = *(const short8*)(Vp + ((size_t)(2 * wc + 0) * 4 + 0) * 512 + lane * 8);
        pb[1] = *(const short8*)(Vp + ((size_t)(2 * wc + 1) * 4 + 0) * 512 + lane * 8);
        pb[2] = *(const short8*)(Up + ((size_t)(2 * wc + 0) * 4 + 0) * 512 + lane * 8);
        pb[3] = *(const short8*)(Up + ((size_t)(2 * wc + 1) * 4 + 0) * 512 + lane * 8);
        #pragma unroll
        for (int kc = 0; kc < 4; ++kc) {
            int k = kc * 32 + g4 * 8;
            short8 a0 = *(const short8*)&Xbuf[swz(32 * wr + t16,      k, 128)];
            short8 a1 = *(const short8*)&Xbuf[swz(32 * wr + 16 + t16, k, 128)];
            short8 b0 = pb[0], b1 = pb[1], b2 = pb[2], b3 = pb[3];
            if (kc < 3) {
                pb[0] = *(const short8*)(Vp + ((size_t)(2 * wc + 0) * 4 + kc + 1) * 512 + lane * 8);
                pb[1] = *(const short8*)(Vp + ((size_t)(2 * wc + 1) * 4 + kc + 1) * 512 + lane * 8);
                pb[2] = *(const short8*)(Up + ((size_t)(2 * wc + 0) * 4 + kc + 1) * 512 + lane * 8);
                pb[3] = *(const short8*)(Up + ((size_t)(2 * wc + 1) * 4 + kc + 1) * 512 + lane * 8);
            }
            acc[0][0] = __builtin_amdgcn_mfma_f32_16x16x32_bf16(a0, b0, acc[0][0], 0, 0, 0);
            acc[1][0] = __builtin_amdgcn_mfma_f32_16x16x32_bf16(a1, b0, acc[1][0], 0, 0, 0);
            acc[0][1] = __builtin_amdgcn_mfma_f32_16x16x32_bf16(a0, b1, acc[0][1], 0, 0, 0);
            acc[1][1] = __builtin_amdgcn_mfma_f32_16x16x32_bf16(a1, b1, acc[1][1], 0, 0, 0);
            acc[0][2] = __builtin_amdgcn_mfma_f32_16x16x32_bf16(a0, b2, acc[0][2], 0, 0, 0);
            acc[1][2] = __builtin_amdgcn_mfma_f32_16x16x32_bf16(a1, b2, acc[1][2], 0, 0, 0);
            acc[0][3] = __builtin_amdgcn_mfma_f32_16x16x32_bf16(a0, b3, acc[0][3], 0, 0, 0);
            acc[1][3] = __builtin_amdgcn_mfma_f32_16x16x32_bf16(a1, b3, acc[1][3], 0, 0, 0);
        }
    }

    // ---- score s = sum_h relu(v)*sigmoid(u)*W_w + W_b  (Abuf now free -> sPb) ----
    #pragma unroll
    for (int m = 0; m < 2; ++m)
        #pragma unroll
        for (int r = 0; r < 4; ++r) {
            float p = 0.0f;
            #pragma unroll
            for (int n = 0; n < 2; ++n) {
                int h = 32 * wc + 16 * n + t16;
                float vv = fmaxf(acc[m][n][r] + V_b[h], 0.0f);
                float uu = sigmoidf_(acc[m][n + 2][r] + U_b[h]);
                p = fmaf(vv * uu, W_w[h], p);
            }
            p += __shfl_xor(p, 1);
            p += __shfl_xor(p, 2);
            p += __shfl_xor(p, 4);
            p += __shfl_xor(p, 8);
            if (t16 == 0) sPb[wc * 64 + 32 * wr + 16 * m + 4 * g4 + r] = p;
        }
    __syncthreads();
    if (tid < TM) {
        float s = sPb[tid] + sPb[64 + tid] + W_b[0];
        sSb[tid] = s;
        s_out[(size_t)b * N_ + tok0 + tid] = s;
    }
    __syncthreads();

    // ---- Phase F: zpart[k] = sum_t s[t] * ffeat[t][k] ----
    {
        int k = tid & 127, q = tid >> 7;     // q in {0,1}
        float z = 0.0f;
        #pragma unroll
        for (int t = 0; t < 32; ++t) {
            int row = q * 32 + t;
            z = fmaf(sSb[row], bf2f(Xbuf[swz(row, k, 128)]), z);
        }
        zqb[q * 128 + k] = z;
    }
    __syncthreads();
    if (tid < 128)
        zpart[(size_t)bx * 128 + tid] = zqb[tid] + zqb[128 + tid];
}

// Grid: 32 blocks, 128 threads.
__global__ __launch_bounds__(128)
void reduce_logits(const float* __restrict__ zpart,
                   const float* __restrict__ cls_w, const float* __restrict__ cls_b,
                   float* __restrict__ out)
{
    __shared__ float sZ[128];
    int b = blockIdx.x, k = threadIdx.x;
    float z = 0.0f;
    #pragma unroll
    for (int t = 0; t < 32; ++t) z += zpart[(size_t)(b * 32 + t) * 128 + k];
    sZ[k] = z;
    __syncthreads();
    if (k < 2) {
        float acc = cls_b[k];
        for (int i = 0; i < 128; ++i) acc = fmaf(sZ[i], cls_w[k * 128 + i], acc);
        out[(size_t)B_ * N_ + b * 2 + k] = acc;
    }
}

extern "C" void kernel_launch(void* const* d_in, const int* in_sizes, int n_in,
                              void* d_out, int out_size, void* d_ws, size_t ws_size,
                              hipStream_t stream) {
    const float* vfeat = (const float*)d_in[0];
    const float* afeat = (const float*)d_in[1];
    const float* vfc_w = (const float*)d_in[2];
    const float* vfc_b = (const float*)d_in[3];
    const float* afc_w = (const float*)d_in[4];
    const float* afc_b = (const float*)d_in[5];
    const float* am_w  = (const float*)d_in[6];
    const float* am_b  = (const float*)d_in[7];
    const float* U_w   = (const float*)d_in[8];
    const float* U_b   = (const float*)d_in[9];
    const float* V_w   = (const float*)d_in[10];
    const float* V_b   = (const float*)d_in[11];
    const float* W_w   = (const float*)d_in[12];
    const float* W_b   = (const float*)d_in[13];
    const float* cls_w = (const float*)d_in[14];
    const float* cls_b = (const float*)d_in[15];

    float* out   = (float*)d_out;
    ushort* wsW  = (ushort*)d_ws;                            // 229376 B packed bf16 weights
    float* zpart = (float*)((char*)d_ws + (size_t)WTOT * 2); // 1024*128*4 = 512 KB

    cvt_weights<<<dim3((WTOT / 8 + 255) / 256), dim3(256), 0, stream>>>(vfc_w, afc_w, am_w, V_w, U_w, wsW);
    fused_mil<<<dim3(B_ * 32), dim3(THREADS), 0, stream>>>(
        vfeat, afeat, wsW, afc_b, am_b, vfc_b, V_b, U_b, W_w, W_b, out, zpart);
    reduce_logits<<<dim3(B_), dim3(128), 0, stream>>>(zpart, cls_w, cls_b, out);
}